// Round 2
// baseline (8084.998 us; speedup 1.0000x reference)
//
#include <hip/hip_runtime.h>

// ---------------------------------------------------------------------------
// AttentionEncoder: B=256, T=512, D=64, H=128
// Per-b independent 512-step attention-LSTM recurrence.
// Kernel 1: transpose weights (coalesced matvec layout) + fuse biases.
// Kernel 2: s2[b,d,s] = sum_t X[b,t,d]*W2[s,t] + b2[s]   (batched GEMM)
// Kernel 3: the recurrence, 1 block per b, s2[b] staged in LDS (128 KB).
// ---------------------------------------------------------------------------

__device__ __forceinline__ float fast_tanh(float x) {
  x = fminf(fmaxf(x, -15.f), 15.f);
  float e = __expf(2.f * x);
  return __fdividef(e - 1.f, e + 1.f);
}
__device__ __forceinline__ float sigm(float x) {
  return __fdividef(1.f, 1.f + __expf(-x));
}

// ---- weight transpose + bias fusion ---------------------------------------
__global__ __launch_bounds__(256) void prep_kernel(
    const float* __restrict__ W1, const float* __restrict__ Whh,
    const float* __restrict__ Wih, const float* __restrict__ bih,
    const float* __restrict__ bhh, float* __restrict__ W1T,
    float* __restrict__ WhhT, float* __restrict__ WihT, float* __restrict__ bz) {
  int i = blockIdx.x * 256 + threadIdx.x;
  if (i < 512 * 256) { int t = i >> 8, j = i & 255; W1T[j * 512 + t] = W1[i]; }
  if (i < 512 * 128) { int k = i >> 7, j = i & 127; WhhT[j * 512 + k] = Whh[i]; }
  if (i < 512 * 64)  { int k = i >> 6, d = i & 63;  WihT[d * 512 + k] = Wih[i]; }
  if (i < 512)       { bz[i] = bih[i] + bhh[i]; }
}

// ---- s2 = einsum('btd,st->bds') + b2 --------------------------------------
// grid (8, 256): blockIdx.y = b, blockIdx.x = 64-wide s-tile. 256 threads.
__global__ __launch_bounds__(256) void s2_kernel(
    const float* __restrict__ X, const float* __restrict__ W2,
    const float* __restrict__ b2, float* __restrict__ s2) {
  __shared__ float Xs[64 * 68];    // [tt][dd], padded row (17 float4s)
  __shared__ float W2sT[64 * 68];  // [tt][ss], padded row
  const int b = blockIdx.y;
  const int s0 = blockIdx.x * 64;
  const int tid = threadIdx.x;
  const int dq = tid & 15, sq = tid >> 4;
  float acc[4][4] = {{0.f, 0.f, 0.f, 0.f}};

  for (int t0 = 0; t0 < 512; t0 += 64) {
    __syncthreads();
    for (int i = tid; i < 4096; i += 256) {
      int tt = i >> 6, dd = i & 63;
      Xs[tt * 68 + dd] = X[((size_t)b * 512 + t0 + tt) * 64 + dd];
      int ss = i >> 6, t2 = i & 63;
      W2sT[t2 * 68 + ss] = W2[(size_t)(s0 + ss) * 512 + t0 + t2];
    }
    __syncthreads();
    const float4* Xs4 = (const float4*)Xs;
    const float4* W4 = (const float4*)W2sT;
#pragma unroll 8
    for (int tt = 0; tt < 64; ++tt) {
      float4 xv = Xs4[tt * 17 + dq];
      float4 wv = W4[tt * 17 + sq];
      float xa[4] = {xv.x, xv.y, xv.z, xv.w};
      float wa[4] = {wv.x, wv.y, wv.z, wv.w};
#pragma unroll
      for (int q = 0; q < 4; ++q)
#pragma unroll
        for (int r = 0; r < 4; ++r) acc[q][r] += xa[q] * wa[r];
    }
  }
  const float* bp = b2 + s0 + sq * 4;
  float b0 = bp[0], bx1 = bp[1], bx2 = bp[2], bx3 = bp[3];
#pragma unroll
  for (int q = 0; q < 4; ++q) {
    float4 o = make_float4(acc[q][0] + b0, acc[q][1] + bx1,
                           acc[q][2] + bx2, acc[q][3] + bx3);
    *(float4*)&s2[((size_t)b * 64 + dq * 4 + q) * 512 + s0 + sq * 4] = o;
  }
}

// ---- the recurrence -------------------------------------------------------
// grid 256 (one block per b), 512 threads (8 waves).
__global__ __launch_bounds__(512) void rnn_kernel(
    const float* __restrict__ X, const float* __restrict__ s2g,
    const float* __restrict__ W1T, const float* __restrict__ WhhT,
    const float* __restrict__ WihT, const float* __restrict__ b1,
    const float* __restrict__ bz, const float* __restrict__ W3,
    const float* __restrict__ b3p, float* __restrict__ out) {
  __shared__ float4 s2s4[64 * 128];  // 128 KB: s2[b] rows d, 512 f32 each
  __shared__ float4 hc4[64];         // [h(128); c(128)]
  __shared__ float4 s1s4[128];
  __shared__ float4 w3s4[128];
  __shared__ float4 xb4[16];
  __shared__ float eb[64];
  __shared__ float zb[512];

  float* hc = (float*)hc4;
  float* s1s = (float*)s1s4;
  float* w3s = (float*)w3s4;
  float* xb = (float*)xb4;

  const int b = blockIdx.x;
  const int tid = threadIdx.x;
  const int lane = tid & 63;
  const int w = tid >> 6;

  {
    const float4* src = (const float4*)(s2g + (size_t)b * 32768);
    for (int i = tid; i < 8192; i += 512) s2s4[i] = src[i];
  }
  if (tid < 64) hc4[tid] = make_float4(0.f, 0.f, 0.f, 0.f);
  w3s[tid] = W3[tid];
  const float b1r = b1[tid];
  const float bzr = bz[tid];
  const float b3v = b3p[0];
  __syncthreads();

  for (int t = 0; t < 512; ++t) {
    // phase 1: s1[tid] = [h;c] . W1[tid,:] + b1  (coalesced W1T stream)
    float acc = b1r;
#pragma unroll 8
    for (int j4 = 0; j4 < 64; ++j4) {
      float4 hv = hc4[j4];
      const float* wp = W1T + (j4 * 4) * 512 + tid;
      acc += hv.x * wp[0] + hv.y * wp[512] + hv.z * wp[1024] + hv.w * wp[1536];
    }
    s1s[tid] = acc;
    __syncthreads();

    // phase 2: e[d] = sum_t tanh(s1[t] + s2[d,t]) * w3[t] + b3
#pragma unroll
    for (int d = w; d < 64; d += 8) {
      float local = 0.f;
#pragma unroll
      for (int i = 0; i < 2; ++i) {
        int f4 = lane + 64 * i;
        float4 sv = s1s4[f4];
        float4 s2v = s2s4[d * 128 + f4];
        float4 wv = w3s4[f4];
        local += fast_tanh(sv.x + s2v.x) * wv.x;
        local += fast_tanh(sv.y + s2v.y) * wv.y;
        local += fast_tanh(sv.z + s2v.z) * wv.z;
        local += fast_tanh(sv.w + s2v.w) * wv.w;
      }
#pragma unroll
      for (int off = 32; off; off >>= 1) local += __shfl_xor(local, off);
      if (lane == 0) eb[d] = local + b3v;
    }
    __syncthreads();

    // phase 3: softmax over d (64) + x = a * x_t   (wave 0 only)
    if (w == 0) {
      float e = eb[lane];
      float m = e;
#pragma unroll
      for (int off = 32; off; off >>= 1) m = fmaxf(m, __shfl_xor(m, off));
      float p = __expf(e - m);
      float s = p;
#pragma unroll
      for (int off = 32; off; off >>= 1) s += __shfl_xor(s, off);
      xb[lane] = __fdividef(p, s) * X[((size_t)b * 512 + t) * 64 + lane];
    }
    __syncthreads();

    // phase 4: z[tid] = x . Wih[tid,:] + h . Whh[tid,:] + bih + bhh
    float zacc = bzr;
#pragma unroll 4
    for (int d4 = 0; d4 < 16; ++d4) {
      float4 xv = xb4[d4];
      const float* wp = WihT + (d4 * 4) * 512 + tid;
      zacc += xv.x * wp[0] + xv.y * wp[512] + xv.z * wp[1024] + xv.w * wp[1536];
    }
#pragma unroll 8
    for (int j4 = 0; j4 < 32; ++j4) {
      float4 hv = hc4[j4];
      const float* wp = WhhT + (j4 * 4) * 512 + tid;
      zacc += hv.x * wp[0] + hv.y * wp[512] + hv.z * wp[1024] + hv.w * wp[1536];
    }
    zb[tid] = zacc;
    __syncthreads();

    // phase 5: LSTM gates, write h
    if (tid < 128) {
      float iv = zb[tid], fv = zb[tid + 128], gv = zb[tid + 256], ov = zb[tid + 384];
      float c = hc[128 + tid];
      float cn = sigm(fv) * c + sigm(iv) * fast_tanh(gv);
      float hn = sigm(ov) * fast_tanh(cn);
      hc[tid] = hn;
      hc[128 + tid] = cn;
      out[((size_t)b * 512 + t) * 128 + tid] = hn;
    }
    __syncthreads();
  }
}

extern "C" void kernel_launch(void* const* d_in, const int* in_sizes, int n_in,
                              void* d_out, int out_size, void* d_ws, size_t ws_size,
                              hipStream_t stream) {
  const float* X   = (const float*)d_in[0];
  const float* Wih = (const float*)d_in[1];
  const float* Whh = (const float*)d_in[2];
  const float* bih = (const float*)d_in[3];
  const float* bhh = (const float*)d_in[4];
  const float* W1  = (const float*)d_in[5];
  const float* b1  = (const float*)d_in[6];
  const float* W2  = (const float*)d_in[7];
  const float* b2  = (const float*)d_in[8];
  const float* W3  = (const float*)d_in[9];
  const float* b3  = (const float*)d_in[10];
  float* out = (float*)d_out;
  float* ws = (float*)d_ws;

  float* s2   = ws;                 // 256*64*512       = 8388608 f32
  float* W1T  = ws + 8388608;       // 256*512          = 131072
  float* WhhT = ws + 8519680;       // 128*512          = 65536
  float* WihT = ws + 8585216;       // 64*512           = 32768
  float* bz   = ws + 8617984;       // 512
  // total: 8618496 floats = 34.5 MB of ws

  hipLaunchKernelGGL(prep_kernel, dim3(512), dim3(256), 0, stream,
                     W1, Whh, Wih, bih, bhh, W1T, WhhT, WihT, bz);
  hipLaunchKernelGGL(s2_kernel, dim3(8, 256), dim3(256), 0, stream,
                     X, W2, b2, s2);
  hipLaunchKernelGGL(rnn_kernel, dim3(256), dim3(512), 0, stream,
                     X, s2, W1T, WhhT, WihT, b1, bz, W3, b3, out);
}